// Round 10
// baseline (234.833 us; speedup 1.0000x reference)
//
#include <hip/hip_runtime.h>
#include <math.h>

#define NN 50000
#define SCL 0.08838834764831845f   // 1/sqrt(128)

// ---- ws layout ----
// f32 region (float offsets)
#define QC    0          // [128] time2vec(0)@Wq_bot
#define CQK   128        // [64]  SCL * Wk_bot @ qconst
#define WT    192        // [64]  [w0, W...]
#define BT    256        // [64]  [b0, B...]
#define UBASE 320        // ushort region base (byte 1280, 16B aligned)
// ushort offsets within ub
#define QXB   0          // [50000*128] bf16 (x@Wq_top + qconst)*SCL
#define KXB   6400000    // [50000*128] bf16 x@Wk_top
#define VOB   12800000   // [50000*128] bf16 x@(Wv_top@Wo)
#define QKXB  19200000   // [50000*64]  bf16 x@Mqk + cqk
#define WCAT  22400000   // [448][128]  bf16 weights [col][k]
#define WVOP  22457344   // [64][64] u32-packed bf16 pairs (wvo[j][2hp],[2hp+1])

typedef __attribute__((ext_vector_type(8))) short bf16x8;
typedef __attribute__((ext_vector_type(4))) float f32x4;

__device__ __forceinline__ float bfl(unsigned int u) {   // low bf16 -> f32
  union { unsigned int i; float f; } v; v.i = u << 16; return v.f;
}
__device__ __forceinline__ float bfh(unsigned int u) {   // high bf16 -> f32
  union { unsigned int i; float f; } v; v.i = u & 0xffff0000u; return v.f;
}
__device__ __forceinline__ unsigned short f2bf(float f) {
  union { float f; unsigned int i; } v; v.f = f;
  return (unsigned short)((v.i + 0x7fff + ((v.i >> 16) & 1)) >> 16);  // RNE
}

// ---------------- prep: ALL weight folding + bf16 packing in one pass ----------------
__global__ __launch_bounds__(128) void tgat_prep(
    const float* __restrict__ Wq, const float* __restrict__ Wk,
    const float* __restrict__ Wv, const float* __restrict__ Wo,
    const float* __restrict__ t2v_w0, const float* __restrict__ t2v_b0,
    const float* __restrict__ t2v_W, const float* __restrict__ t2v_B,
    float* __restrict__ ws, unsigned short* __restrict__ ub) {
  const int h = threadIdx.x;
  const int b = blockIdx.x;
  __shared__ float row_s[128];

  if (b < 128) {
    // Wvo_top row b -> WCAT col 256+h, k=b (bf16 scatter)
    const float* wvrow = Wv + b * 128;
    float acc = 0.f;
#pragma unroll 8
    for (int f = 0; f < 128; ++f) acc += wvrow[f] * Wo[f * 128 + h];
    ub[WCAT + (256 + h) * 128 + b] = f2bf(acc);
  } else if (b < 192) {
    // Wvo_bot row j -> packed WVOP[j][hp]
    const int j = b - 128;
    const float* wvrow = Wv + (128 + j) * 128;
    float acc = 0.f;
#pragma unroll 8
    for (int f = 0; f < 128; ++f) acc += wvrow[f] * Wo[f * 128 + h];
    row_s[h] = acc;
    __syncthreads();
    if (h < 64) {
      unsigned* wp = (unsigned*)(ub + WVOP);
      wp[j * 64 + h] = (unsigned)f2bf(row_s[2 * h]) |
                       ((unsigned)f2bf(row_s[2 * h + 1]) << 16);
    }
  } else if (b == 192) {
    // qconst = time2vec(0) @ Wq_bot
    float acc = t2v_b0[0] * Wq[128 * 128 + h];
    for (int j = 1; j < 64; ++j)
      acc += __sinf(t2v_B[j - 1]) * Wq[(128 + j) * 128 + h];
    ws[QC + h] = acc;
  } else if (b < 321) {
    // Mqk[f][j] -> WCAT col 384+j, k=f
    const int f = b - 193;
    if (h < 64) {
      const float* wqrow = Wq + f * 128;
      const float* wkrow = Wk + (128 + h) * 128;
      float acc = 0.f;
#pragma unroll 8
      for (int i = 0; i < 128; ++i) acc += wqrow[i] * wkrow[i];
      ub[WCAT + (384 + h) * 128 + f] = f2bf(SCL * acc);
    }
  } else if (b < 577) {
    // Wq/Wk columns -> WCAT cols 0..255
    const int c = b - 321;
    const float v = (c < 128) ? Wq[h * 128 + c] : Wk[h * 128 + (c - 128)];
    ub[WCAT + c * 128 + h] = f2bf(v);
  } else {
    if (h < 64) {
      ws[WT + h] = (h == 0) ? t2v_w0[0] : t2v_W[h - 1];
      ws[BT + h] = (h == 0) ? t2v_b0[0] : t2v_B[h - 1];
    }
  }
}

// ---------------- prep2: cqk (needs QC) ----------------
__global__ __launch_bounds__(64) void tgat_prep2(
    const float* __restrict__ Wk, float* __restrict__ ws) {
  const int j = threadIdx.x;
  const float* wkrow = Wk + (128 + j) * 128;
  float acc = 0.f;
#pragma unroll 8
  for (int i = 0; i < 128; ++i) acc += ws[QC + i] * wkrow[i];
  ws[CQK + j] = SCL * acc;
}

// ---------------- precomp: [50000,128]@[128,448]; 16 rows/block, ct split across 4 waves ----------------
__global__ __launch_bounds__(256) void tgat_precomp_mfma(
    const float* __restrict__ x, float* ws) {
  const int lane = threadIdx.x & 63;
  const int wv = threadIdx.x >> 6;
  const int mr = blockIdx.x * 16;        // 3125 blocks * 16 = 50000 exactly
  unsigned short* ub = (unsigned short*)(ws + UBASE);
  const unsigned short* wc = ub + WCAT;
  const int arow = lane & 15;
  const int ko = (lane >> 4) * 8;
  const int rbase = (lane >> 4) * 4;

  // A fragments (each wave loads its block's 16 rows; 4x re-read is L2-hot)
  bf16x8 afr[4];
  {
    const float* xrow = x + (size_t)(mr + arow) * 128;
#pragma unroll
    for (int kk = 0; kk < 4; ++kk) {
      const float4 lo = *(const float4*)(xrow + kk * 32 + ko);
      const float4 hi = *(const float4*)(xrow + kk * 32 + ko + 4);
      bf16x8 f;
      f[0] = (short)f2bf(lo.x); f[1] = (short)f2bf(lo.y);
      f[2] = (short)f2bf(lo.z); f[3] = (short)f2bf(lo.w);
      f[4] = (short)f2bf(hi.x); f[5] = (short)f2bf(hi.y);
      f[6] = (short)f2bf(hi.z); f[7] = (short)f2bf(hi.w);
      afr[kk] = f;
    }
  }

  unsigned short* qxb  = ub + QXB;
  unsigned short* kxb  = ub + KXB;
  unsigned short* vob  = ub + VOB;
  unsigned short* qkxb = ub + QKXB;

  // wave wv owns column-tiles [wv*7, wv*7+7)
#pragma unroll
  for (int c7 = 0; c7 < 7; ++c7) {
    const int ct = wv * 7 + c7;
    const int col = ct * 16 + arow;
    bf16x8 bfr[4];
#pragma unroll
    for (int kk = 0; kk < 4; ++kk)
      bfr[kk] = *(const bf16x8*)(wc + (size_t)col * 128 + kk * 32 + ko);
    f32x4 acc = {0.f, 0.f, 0.f, 0.f};
#pragma unroll
    for (int kk = 0; kk < 4; ++kk)
      acc = __builtin_amdgcn_mfma_f32_16x16x32_bf16(afr[kk], bfr[kk], acc, 0, 0, 0);

    const int gc = ct * 16 + arow;       // output column (cl == arow)
    if (ct < 8) {
      const float qc = ws[QC + gc];
#pragma unroll
      for (int r = 0; r < 4; ++r)
        qxb[(size_t)(mr + rbase + r) * 128 + gc] = f2bf((acc[r] + qc) * SCL);
    } else if (ct < 16) {
#pragma unroll
      for (int r = 0; r < 4; ++r)
        kxb[(size_t)(mr + rbase + r) * 128 + (gc - 128)] = f2bf(acc[r]);
    } else if (ct < 24) {
#pragma unroll
      for (int r = 0; r < 4; ++r)
        vob[(size_t)(mr + rbase + r) * 128 + (gc - 256)] = f2bf(acc[r]);
    } else {
      const float cq = ws[CQK + gc - 384];
#pragma unroll
      for (int r = 0; r < 4; ++r)
        qkxb[(size_t)(mr + rbase + r) * 64 + (gc - 384)] = f2bf(acc[r] + cq);
    }
  }
}

// ---------------- main: one wave per node; barrier-free; GEMV wvo from L2 ----------------
__global__ __launch_bounds__(256, 6) void tgat_main(
    const float* __restrict__ ts, const int* __restrict__ idx,
    const float* __restrict__ bo, const float* __restrict__ ws,
    float* __restrict__ out) {
  const int lane = threadIdx.x & 63;
  const int wv   = threadIdx.x >> 6;
  const int my_k = lane >> 2, my_c = lane & 3;

  __shared__ float lds[4 * 1312];
  float* te_s = lds + wv * 1312;        // [64 j][17] (col = k, pad)
  float* s_s  = te_s + 1088;            // [16]
  float* q_s  = te_s + 1104;            // [4 blocks][36] (stride-36 => conflict-free f4)
  float* qk_s = te_s + 1248;            // [64]; reused for tagg after score

  const unsigned short* ubr = (const unsigned short*)(ws + UBASE);
  const unsigned short* qxb  = ubr + QXB;
  const unsigned short* kxb  = ubr + KXB;
  const unsigned short* vob  = ubr + VOB;
  const unsigned short* qkxb = ubr + QKXB;
  const unsigned* wvp = (const unsigned*)(ubr + WVOP);   // 16 KB, L2-resident

  const int n = blockIdx.x * 4 + wv;     // 12500 * 4 = 50000 exactly

  // ---- issue all per-node memory up front ----
  const int   iv = idx[n * 16 + (lane & 15)];
  const float tv = ts[n * 16 + (lane & 15)];
  const unsigned qu = ((const unsigned*)(qxb + (size_t)n * 128))[lane];  // q[2l],q[2l+1]
  unsigned qku = 0;
  if (lane < 32) qku = ((const unsigned*)(qkxb + (size_t)n * 64))[lane];
  const float2 bo2 = ((const float2*)bo)[lane];

  const int i_myk = __shfl(iv, my_k, 64);
  const unsigned short* kr = kxb + (size_t)i_myk * 128 + my_c * 32;
  const uint4 kx0 = *(const uint4*)(kr);
  const uint4 kx1 = *(const uint4*)(kr + 8);
  const uint4 kx2 = *(const uint4*)(kr + 16);
  const uint4 kx3 = *(const uint4*)(kr + 24);
  unsigned int vg[16];
#pragma unroll
  for (int k = 0; k < 16; ++k) {
    const int ik = __shfl(iv, k, 64);
    vg[k] = ((const unsigned int*)(vob + (size_t)ik * 128))[lane];
  }

  // ---- time2vec (coeffs transient; L2-hot) ----
  const float tvk = __shfl(tv, my_k, 64);
  float te[16];
  {
    const float4* w4 = (const float4*)(ws + WT + my_c * 16);
    const float4* b4 = (const float4*)(ws + BT + my_c * 16);
#pragma unroll
    for (int i4 = 0; i4 < 4; ++i4) {
      const float4 a = w4[i4], b = b4[i4];
      te[i4*4+0] = __sinf(tvk * a.x + b.x);
      te[i4*4+1] = __sinf(tvk * a.y + b.y);
      te[i4*4+2] = __sinf(tvk * a.z + b.z);
      te[i4*4+3] = __sinf(tvk * a.w + b.w);
    }
  }
  if (my_c == 0) te[0] = tvk * (ws[WT]) + ws[BT];   // j==0 linear term

  // ---- stage q/qk/te into wave-private LDS ----
  {
    const int f = 2 * lane;
    const int qi = (f >> 5) * 36 + (f & 31);
    q_s[qi] = bfl(qu); q_s[qi + 1] = bfh(qu);
  }
  if (lane < 32) { qk_s[2 * lane] = bfl(qku); qk_s[2 * lane + 1] = bfh(qku); }
#pragma unroll
  for (int i = 0; i < 16; ++i)
    te_s[(my_c * 16 + i) * 17 + my_k] = te[i];
  asm volatile("s_waitcnt lgkmcnt(0)" ::: "memory");

  // ---- score: s_k = q . kx[idx_k] (32 feats/lane) + te . qk (16 feats/lane) ----
  float p = 0.f;
  {
    const float4* qb = (const float4*)(q_s + my_c * 36);
#pragma unroll
    for (int q8 = 0; q8 < 4; ++q8) {
      const uint4 u = (q8 == 0) ? kx0 : (q8 == 1) ? kx1 : (q8 == 2) ? kx2 : kx3;
      const float4 qlo = qb[q8 * 2], qhi = qb[q8 * 2 + 1];
      p += bfl(u.x) * qlo.x + bfh(u.x) * qlo.y;
      p += bfl(u.y) * qlo.z + bfh(u.y) * qlo.w;
      p += bfl(u.z) * qhi.x + bfh(u.z) * qhi.y;
      p += bfl(u.w) * qhi.z + bfh(u.w) * qhi.w;
    }
    const float4* qq4 = (const float4*)(qk_s + my_c * 16);
#pragma unroll
    for (int i4 = 0; i4 < 4; ++i4) {
      const float4 q = qq4[i4];
      p += te[i4*4+0]*q.x + te[i4*4+1]*q.y + te[i4*4+2]*q.z + te[i4*4+3]*q.w;
    }
  }
  p += __shfl_xor(p, 1, 64);
  p += __shfl_xor(p, 2, 64);
  if (my_c == 0) s_s[my_k] = p;
  asm volatile("s_waitcnt lgkmcnt(0)" ::: "memory");

  // ---- softmax over 16 (redundant per lane; broadcast reads) ----
  float a[16];
  {
    float sv[16];
    const float4* s4 = (const float4*)s_s;
#pragma unroll
    for (int i4 = 0; i4 < 4; ++i4) {
      const float4 v = s4[i4];
      sv[i4*4+0]=v.x; sv[i4*4+1]=v.y; sv[i4*4+2]=v.z; sv[i4*4+3]=v.w;
    }
    float m = sv[0];
#pragma unroll
    for (int k = 1; k < 16; ++k) m = fmaxf(m, sv[k]);
    float sum = 0.f;
#pragma unroll
    for (int k = 0; k < 16; ++k) { a[k] = __expf(sv[k] - m); sum += a[k]; }
    const float inv = 1.f / sum;
#pragma unroll
    for (int k = 0; k < 16; ++k) a[k] *= inv;
  }

  // ---- tagg[j=lane] = sum_k a_k te[k][j] -> qk_s (wave-private reuse) ----
  {
    float ta = 0.f;
#pragma unroll
    for (int k = 0; k < 16; ++k) ta += a[k] * te_s[lane * 17 + k];
    qk_s[lane] = ta;
  }
  asm volatile("s_waitcnt lgkmcnt(0)" ::: "memory");

  // ---- vo aggregation: acc_h = bo_h + sum_k a_k vo[idx_k][h], h = 2lane,2lane+1 ----
  float acc0 = bo2.x, acc1 = bo2.y;
#pragma unroll
  for (int k = 0; k < 16; ++k) {
    const unsigned int u = vg[k];
    acc0 += a[k] * bfl(u);
    acc1 += a[k] * bfh(u);
  }

  // ---- fused output GEMV: acc += tagg @ Wvo_bot[:, h] (wvo pairs from L2, coalesced) ----
  {
    const float4* ta4 = (const float4*)qk_s;
#pragma unroll
    for (int j4 = 0; j4 < 16; ++j4) {
      const float4 tb = ta4[j4];        // LDS broadcast read
      const unsigned u0 = wvp[(j4*4+0) * 64 + lane];
      const unsigned u1 = wvp[(j4*4+1) * 64 + lane];
      const unsigned u2 = wvp[(j4*4+2) * 64 + lane];
      const unsigned u3 = wvp[(j4*4+3) * 64 + lane];
      acc0 += tb.x * bfl(u0); acc1 += tb.x * bfh(u0);
      acc0 += tb.y * bfl(u1); acc1 += tb.y * bfh(u1);
      acc0 += tb.z * bfl(u2); acc1 += tb.z * bfh(u2);
      acc0 += tb.w * bfl(u3); acc1 += tb.w * bfh(u3);
    }
  }

  float2 o; o.x = fmaxf(acc0, 0.f); o.y = fmaxf(acc1, 0.f);
  ((float2*)(out + (size_t)n * 128))[lane] = o;
}

extern "C" void kernel_launch(void* const* d_in, const int* in_sizes, int n_in,
                              void* d_out, int out_size, void* d_ws, size_t ws_size,
                              hipStream_t stream) {
  const float* x    = (const float*)d_in[0];
  const float* ts   = (const float*)d_in[1];
  const int*   idx  = (const int*)  d_in[2];
  const float* w0   = (const float*)d_in[3];
  const float* b0   = (const float*)d_in[4];
  const float* t2vW = (const float*)d_in[5];
  const float* t2vB = (const float*)d_in[6];
  const float* Wq   = (const float*)d_in[7];
  const float* Wk   = (const float*)d_in[8];
  const float* Wv   = (const float*)d_in[9];
  const float* Wo   = (const float*)d_in[10];
  const float* bo   = (const float*)d_in[11];
  float* ws = (float*)d_ws;                      // ~45 MB used
  unsigned short* ub = (unsigned short*)(ws + UBASE);
  float* out = (float*)d_out;

  tgat_prep<<<578, 128, 0, stream>>>(Wq, Wk, Wv, Wo, w0, b0, t2vW, t2vB, ws, ub);
  tgat_prep2<<<1, 64, 0, stream>>>(Wk, ws);
  tgat_precomp_mfma<<<3125, 256, 0, stream>>>(x, ws);
  tgat_main<<<12500, 256, 0, stream>>>(ts, idx, bo, ws, out);
}

// Round 11
// 215.246 us; speedup vs baseline: 1.0910x; 1.0910x over previous
//
#include <hip/hip_runtime.h>
#include <math.h>

#define NN 50000
#define SCL 0.08838834764831845f   // 1/sqrt(128)

// ---- ws layout ----
// f32 region (float offsets)
#define QC    0          // [128] time2vec(0)@Wq_bot
#define CQK   128        // [64]  SCL * Wk_bot @ qconst
#define WT    192        // [64]  [w0, W...]
#define BT    256        // [64]  [b0, B...]
#define UBASE 320        // ushort region base (byte 1280, 16B aligned)
// ushort offsets within ub
#define QXB   0          // [50000*128] bf16 (x@Wq_top + qconst)*SCL
#define KXB   6400000    // [50000*128] bf16 x@Wk_top
#define VOB   12800000   // [50000*128] bf16 x@(Wv_top@Wo)
#define QKXB  19200000   // [50000*64]  bf16 x@Mqk + cqk
#define WCAT  22400000   // [448][128]  bf16 weights [col][k]
#define WVOP  22457344   // [64][64] u32-packed bf16 pairs (wvo[j][2hp],[2hp+1])

typedef __attribute__((ext_vector_type(8))) short bf16x8;
typedef __attribute__((ext_vector_type(4))) float f32x4;

__device__ __forceinline__ float bfl(unsigned int u) {   // low bf16 -> f32
  union { unsigned int i; float f; } v; v.i = u << 16; return v.f;
}
__device__ __forceinline__ float bfh(unsigned int u) {   // high bf16 -> f32
  union { unsigned int i; float f; } v; v.i = u & 0xffff0000u; return v.f;
}
__device__ __forceinline__ unsigned short f2bf(float f) {
  union { float f; unsigned int i; } v; v.f = f;
  return (unsigned short)((v.i + 0x7fff + ((v.i >> 16) & 1)) >> 16);  // RNE
}

// ---------------- prep: ALL weight folding + bf16 packing + cqk, one kernel ----------------
__global__ __launch_bounds__(128) void tgat_prep(
    const float* __restrict__ Wq, const float* __restrict__ Wk,
    const float* __restrict__ Wv, const float* __restrict__ Wo,
    const float* __restrict__ t2v_w0, const float* __restrict__ t2v_b0,
    const float* __restrict__ t2v_W, const float* __restrict__ t2v_B,
    float* __restrict__ ws, unsigned short* __restrict__ ub) {
  const int h = threadIdx.x;
  const int b = blockIdx.x;
  __shared__ float row_s[128];
  __shared__ float sm_s[64];

  if (b < 128) {
    // Wvo_top row b -> WCAT col 256+h, k=b (bf16 scatter)
    const float* wvrow = Wv + b * 128;
    float acc = 0.f;
#pragma unroll 8
    for (int f = 0; f < 128; ++f) acc += wvrow[f] * Wo[f * 128 + h];
    ub[WCAT + (256 + h) * 128 + b] = f2bf(acc);
  } else if (b < 192) {
    // Wvo_bot row j -> packed WVOP[j][hp]
    const int j = b - 128;
    const float* wvrow = Wv + (128 + j) * 128;
    float acc = 0.f;
#pragma unroll 8
    for (int f = 0; f < 128; ++f) acc += wvrow[f] * Wo[f * 128 + h];
    row_s[h] = acc;
    __syncthreads();
    if (h < 64) {
      unsigned* wp = (unsigned*)(ub + WVOP);
      wp[j * 64 + h] = (unsigned)f2bf(row_s[2 * h]) |
                       ((unsigned)f2bf(row_s[2 * h + 1]) << 16);
    }
  } else if (b == 192) {
    // qconst = time2vec(0) @ Wq_bot  (table copy for precomp epilogue)
    float acc = t2v_b0[0] * Wq[128 * 128 + h];
    for (int j = 1; j < 64; ++j)
      acc += __sinf(t2v_B[j - 1]) * Wq[(128 + j) * 128 + h];
    ws[QC + h] = acc;
  } else if (b < 321) {
    // Mqk[f][j] -> WCAT col 384+j, k=f
    const int f = b - 193;
    if (h < 64) {
      const float* wqrow = Wq + f * 128;
      const float* wkrow = Wk + (128 + h) * 128;
      float acc = 0.f;
#pragma unroll 8
      for (int i = 0; i < 128; ++i) acc += wqrow[i] * wkrow[i];
      ub[WCAT + (384 + h) * 128 + f] = f2bf(SCL * acc);
    }
  } else if (b < 577) {
    // Wq/Wk columns -> WCAT cols 0..255
    const int c = b - 321;
    const float v = (c < 128) ? Wq[h * 128 + c] : Wk[h * 128 + (c - 128)];
    ub[WCAT + c * 128 + h] = f2bf(v);
  } else if (b == 577) {
    if (h < 64) {
      ws[WT + h] = (h == 0) ? t2v_w0[0] : t2v_W[h - 1];
      ws[BT + h] = (h == 0) ? t2v_b0[0] : t2v_B[h - 1];
    }
  } else {
    // cqk: recompute qconst locally (no cross-block dependency), then
    // cqk[j] = SCL * sum_i qconst[i] * Wk_bot[j][i]
    if (h < 64)
      sm_s[h] = (h == 0) ? t2v_b0[0] : __sinf(t2v_B[h - 1]);
    __syncthreads();
    float qc = 0.f;
#pragma unroll 8
    for (int m = 0; m < 64; ++m)
      qc += sm_s[m] * Wq[(128 + m) * 128 + h];   // coalesced row reads
    row_s[h] = qc;
    __syncthreads();
    if (h < 64) {
      const float* wkrow = Wk + (128 + h) * 128;
      float acc = 0.f;
#pragma unroll 8
      for (int i = 0; i < 128; ++i) acc += row_s[i] * wkrow[i];
      ws[CQK + h] = SCL * acc;
    }
  }
}

// ---------------- precomp: [50000,128]@[128,448]; 1 wave = 16 rows x 28 col-tiles ----------------
__global__ __launch_bounds__(64) void tgat_precomp_mfma(
    const float* __restrict__ x, float* ws) {
  const int lane = threadIdx.x;
  const int mr = blockIdx.x * 16;        // 3125 blocks * 16 = 50000 exactly
  unsigned short* ub = (unsigned short*)(ws + UBASE);
  const unsigned short* wc = ub + WCAT;
  const int arow = lane & 15;
  const int ko = (lane >> 4) * 8;
  const int rbase = (lane >> 4) * 4;

  // A fragments: load f32, round to bf16 in registers (loaded ONCE per wave)
  bf16x8 afr[4];
  {
    const float* xrow = x + (size_t)(mr + arow) * 128;
#pragma unroll
    for (int kk = 0; kk < 4; ++kk) {
      const float4 lo = *(const float4*)(xrow + kk * 32 + ko);
      const float4 hi = *(const float4*)(xrow + kk * 32 + ko + 4);
      bf16x8 f;
      f[0] = (short)f2bf(lo.x); f[1] = (short)f2bf(lo.y);
      f[2] = (short)f2bf(lo.z); f[3] = (short)f2bf(lo.w);
      f[4] = (short)f2bf(hi.x); f[5] = (short)f2bf(hi.y);
      f[6] = (short)f2bf(hi.z); f[7] = (short)f2bf(hi.w);
      afr[kk] = f;
    }
  }

  unsigned short* qxb  = ub + QXB;
  unsigned short* kxb  = ub + KXB;
  unsigned short* vob  = ub + VOB;
  unsigned short* qkxb = ub + QKXB;

#pragma unroll 4
  for (int ct = 0; ct < 28; ++ct) {
    const int col = ct * 16 + arow;
    bf16x8 bfr[4];
#pragma unroll
    for (int kk = 0; kk < 4; ++kk)
      bfr[kk] = *(const bf16x8*)(wc + (size_t)col * 128 + kk * 32 + ko);
    f32x4 acc = {0.f, 0.f, 0.f, 0.f};
#pragma unroll
    for (int kk = 0; kk < 4; ++kk)
      acc = __builtin_amdgcn_mfma_f32_16x16x32_bf16(afr[kk], bfr[kk], acc, 0, 0, 0);

    const int gc = ct * 16 + arow;       // output column (cl == arow)
    if (ct < 8) {
      const float qc = ws[QC + gc];
#pragma unroll
      for (int r = 0; r < 4; ++r)
        qxb[(size_t)(mr + rbase + r) * 128 + gc] = f2bf((acc[r] + qc) * SCL);
    } else if (ct < 16) {
#pragma unroll
      for (int r = 0; r < 4; ++r)
        kxb[(size_t)(mr + rbase + r) * 128 + (gc - 128)] = f2bf(acc[r]);
    } else if (ct < 24) {
#pragma unroll
      for (int r = 0; r < 4; ++r)
        vob[(size_t)(mr + rbase + r) * 128 + (gc - 256)] = f2bf(acc[r]);
    } else {
      const float cq = ws[CQK + gc - 384];
#pragma unroll
      for (int r = 0; r < 4; ++r)
        qkxb[(size_t)(mr + rbase + r) * 64 + (gc - 384)] = f2bf(acc[r] + cq);
    }
  }
}

// ---------------- main: one wave per node; fused output GEMV + relu (r9 config) ----------------
__global__ __launch_bounds__(256, 4) void tgat_main(
    const float* __restrict__ ts, const int* __restrict__ idx,
    const float* __restrict__ bo, const float* __restrict__ ws,
    float* __restrict__ out) {
  const int lane = threadIdx.x & 63;
  const int wv   = threadIdx.x >> 6;
  const int my_k = lane >> 2, my_c = lane & 3;

  __shared__ float lds[4 * 1312];
  __shared__ unsigned wvo_l[4096];      // [j][hp] packed bf16 pairs, 16 KB
  float* te_s = lds + wv * 1312;        // [64 j][17] (col = k, pad)
  float* s_s  = te_s + 1088;            // [16]
  float* q_s  = te_s + 1104;            // [4 blocks][36] (stride-36 => conflict-free f4)
  float* qk_s = te_s + 1248;            // [64]; reused for tagg after score

  const unsigned short* ubr = (const unsigned short*)(ws + UBASE);
  const unsigned short* qxb  = ubr + QXB;
  const unsigned short* kxb  = ubr + KXB;
  const unsigned short* vob  = ubr + VOB;
  const unsigned short* qkxb = ubr + QKXB;

  const int n = blockIdx.x * 4 + wv;     // 12500 * 4 = 50000 exactly

  // ---- stage packed Wvo_bot into LDS (block-shared; barrier later) ----
  {
    const uint4* wvp = (const uint4*)(ubr + WVOP);
#pragma unroll
    for (int i = 0; i < 4; ++i)
      ((uint4*)wvo_l)[threadIdx.x + i * 256] = wvp[threadIdx.x + i * 256];
  }

  // ---- issue all per-node memory up front ----
  const int   iv = idx[n * 16 + (lane & 15)];
  const float tv = ts[n * 16 + (lane & 15)];
  const unsigned qu = ((const unsigned*)(qxb + (size_t)n * 128))[lane];  // q[2l],q[2l+1]
  unsigned qku = 0;
  if (lane < 32) qku = ((const unsigned*)(qkxb + (size_t)n * 64))[lane];
  const float2 bo2 = ((const float2*)bo)[lane];

  const int i_myk = __shfl(iv, my_k, 64);
  const unsigned short* kr = kxb + (size_t)i_myk * 128 + my_c * 32;
  const uint4 kx0 = *(const uint4*)(kr);
  const uint4 kx1 = *(const uint4*)(kr + 8);
  const uint4 kx2 = *(const uint4*)(kr + 16);
  const uint4 kx3 = *(const uint4*)(kr + 24);
  unsigned int vg[16];
#pragma unroll
  for (int k = 0; k < 16; ++k) {
    const int ik = __shfl(iv, k, 64);
    vg[k] = ((const unsigned int*)(vob + (size_t)ik * 128))[lane];
  }

  // ---- time2vec (coeffs transient; L2-hot) ----
  const float tvk = __shfl(tv, my_k, 64);
  float te[16];
  {
    const float4* w4 = (const float4*)(ws + WT + my_c * 16);
    const float4* b4 = (const float4*)(ws + BT + my_c * 16);
#pragma unroll
    for (int i4 = 0; i4 < 4; ++i4) {
      const float4 a = w4[i4], b = b4[i4];
      te[i4*4+0] = __sinf(tvk * a.x + b.x);
      te[i4*4+1] = __sinf(tvk * a.y + b.y);
      te[i4*4+2] = __sinf(tvk * a.z + b.z);
      te[i4*4+3] = __sinf(tvk * a.w + b.w);
    }
  }
  if (my_c == 0) te[0] = tvk * (ws[WT]) + ws[BT];   // j==0 linear term

  // ---- stage q/qk/te into wave-private LDS ----
  {
    const int f = 2 * lane;
    const int qi = (f >> 5) * 36 + (f & 31);
    q_s[qi] = bfl(qu); q_s[qi + 1] = bfh(qu);
  }
  if (lane < 32) { qk_s[2 * lane] = bfl(qku); qk_s[2 * lane + 1] = bfh(qku); }
#pragma unroll
  for (int i = 0; i < 16; ++i)
    te_s[(my_c * 16 + i) * 17 + my_k] = te[i];
  asm volatile("s_waitcnt lgkmcnt(0)" ::: "memory");

  // ---- score: s_k = q . kx[idx_k] (32 feats/lane) + te . qk (16 feats/lane) ----
  float p = 0.f;
  {
    const float4* qb = (const float4*)(q_s + my_c * 36);
#pragma unroll
    for (int q8 = 0; q8 < 4; ++q8) {
      const uint4 u = (q8 == 0) ? kx0 : (q8 == 1) ? kx1 : (q8 == 2) ? kx2 : kx3;
      const float4 qlo = qb[q8 * 2], qhi = qb[q8 * 2 + 1];
      p += bfl(u.x) * qlo.x + bfh(u.x) * qlo.y;
      p += bfl(u.y) * qlo.z + bfh(u.y) * qlo.w;
      p += bfl(u.z) * qhi.x + bfh(u.z) * qhi.y;
      p += bfl(u.w) * qhi.z + bfh(u.w) * qhi.w;
    }
    const float4* qq4 = (const float4*)(qk_s + my_c * 16);
#pragma unroll
    for (int i4 = 0; i4 < 4; ++i4) {
      const float4 q = qq4[i4];
      p += te[i4*4+0]*q.x + te[i4*4+1]*q.y + te[i4*4+2]*q.z + te[i4*4+3]*q.w;
    }
  }
  p += __shfl_xor(p, 1, 64);
  p += __shfl_xor(p, 2, 64);
  if (my_c == 0) s_s[my_k] = p;
  asm volatile("s_waitcnt lgkmcnt(0)" ::: "memory");

  // ---- softmax over 16 (redundant per lane; broadcast reads) ----
  float a[16];
  {
    float sv[16];
    const float4* s4 = (const float4*)s_s;
#pragma unroll
    for (int i4 = 0; i4 < 4; ++i4) {
      const float4 v = s4[i4];
      sv[i4*4+0]=v.x; sv[i4*4+1]=v.y; sv[i4*4+2]=v.z; sv[i4*4+3]=v.w;
    }
    float m = sv[0];
#pragma unroll
    for (int k = 1; k < 16; ++k) m = fmaxf(m, sv[k]);
    float sum = 0.f;
#pragma unroll
    for (int k = 0; k < 16; ++k) { a[k] = __expf(sv[k] - m); sum += a[k]; }
    const float inv = 1.f / sum;
#pragma unroll
    for (int k = 0; k < 16; ++k) a[k] *= inv;
  }

  // ---- tagg[j=lane] = sum_k a_k te[k][j] -> qk_s (wave-private reuse) ----
  {
    float ta = 0.f;
#pragma unroll
    for (int k = 0; k < 16; ++k) ta += a[k] * te_s[lane * 17 + k];
    qk_s[lane] = ta;
  }
  asm volatile("s_waitcnt lgkmcnt(0)" ::: "memory");

  // ---- vo aggregation: acc_h = bo_h + sum_k a_k vo[idx_k][h], h = 2lane,2lane+1 ----
  float acc0 = bo2.x, acc1 = bo2.y;
#pragma unroll
  for (int k = 0; k < 16; ++k) {
    const unsigned int u = vg[k];
    acc0 += a[k] * bfl(u);
    acc1 += a[k] * bfh(u);
  }

  // ---- fused output GEMV: acc += tagg @ Wvo_bot[:, h] (wvo in LDS, bf16 pairs) ----
  __syncthreads();                      // wvo_l ready (single block-wide barrier)
  {
    const float4* ta4 = (const float4*)qk_s;
#pragma unroll
    for (int j4 = 0; j4 < 16; ++j4) {
      const float4 tb = ta4[j4];        // broadcast read
      const unsigned u0 = wvo_l[(j4*4+0) * 64 + lane];
      const unsigned u1 = wvo_l[(j4*4+1) * 64 + lane];
      const unsigned u2 = wvo_l[(j4*4+2) * 64 + lane];
      const unsigned u3 = wvo_l[(j4*4+3) * 64 + lane];
      acc0 += tb.x * bfl(u0); acc1 += tb.x * bfh(u0);
      acc0 += tb.y * bfl(u1); acc1 += tb.y * bfh(u1);
      acc0 += tb.z * bfl(u2); acc1 += tb.z * bfh(u2);
      acc0 += tb.w * bfl(u3); acc1 += tb.w * bfh(u3);
    }
  }

  float2 o; o.x = fmaxf(acc0, 0.f); o.y = fmaxf(acc1, 0.f);
  ((float2*)(out + (size_t)n * 128))[lane] = o;
}

extern "C" void kernel_launch(void* const* d_in, const int* in_sizes, int n_in,
                              void* d_out, int out_size, void* d_ws, size_t ws_size,
                              hipStream_t stream) {
  const float* x    = (const float*)d_in[0];
  const float* ts   = (const float*)d_in[1];
  const int*   idx  = (const int*)  d_in[2];
  const float* w0   = (const float*)d_in[3];
  const float* b0   = (const float*)d_in[4];
  const float* t2vW = (const float*)d_in[5];
  const float* t2vB = (const float*)d_in[6];
  const float* Wq   = (const float*)d_in[7];
  const float* Wk   = (const float*)d_in[8];
  const float* Wv   = (const float*)d_in[9];
  const float* Wo   = (const float*)d_in[10];
  const float* bo   = (const float*)d_in[11];
  float* ws = (float*)d_ws;                      // ~45 MB used
  unsigned short* ub = (unsigned short*)(ws + UBASE);
  float* out = (float*)d_out;

  tgat_prep<<<579, 128, 0, stream>>>(Wq, Wk, Wv, Wo, w0, b0, t2vW, t2vB, ws, ub);
  tgat_precomp_mfma<<<3125, 64, 0, stream>>>(x, ws);
  tgat_main<<<12500, 256, 0, stream>>>(ts, idx, bo, ws, out);
}